// Round 1
// baseline (829.307 us; speedup 1.0000x reference)
//
#include <hip/hip_runtime.h>

// Batched Kalman filter: B batches, N=8 state, M=4 measurement, fp32.
// One thread per batch; all matrices in registers, fully unrolled.
// Outputs flat-concatenated: x_new[B*8], P_new[B*64], K[B*32].

#define EPS 1e-6f

__global__ void kf_kernel(const float* __restrict__ x_est,
                          const float* __restrict__ P_est,
                          const float* __restrict__ Fin,
                          const float* __restrict__ Qin,
                          const float* __restrict__ zin,
                          const float* __restrict__ Hin,
                          const float* __restrict__ Rin,
                          float* __restrict__ out, int B) {
    int b = blockIdx.x * blockDim.x + threadIdx.x;
    if (b >= B) return;
    size_t sb = (size_t)b;

    // ---- load F, P (8x8 each) via float4 ----
    float Fr[64], P[64];
    {
        const float4* F4 = reinterpret_cast<const float4*>(Fin + sb * 64);
        const float4* P4 = reinterpret_cast<const float4*>(P_est + sb * 64);
#pragma unroll
        for (int i = 0; i < 16; ++i) {
            float4 f = F4[i];
            Fr[4 * i + 0] = f.x; Fr[4 * i + 1] = f.y; Fr[4 * i + 2] = f.z; Fr[4 * i + 3] = f.w;
        }
#pragma unroll
        for (int i = 0; i < 16; ++i) {
            float4 p = P4[i];
            P[4 * i + 0] = p.x; P[4 * i + 1] = p.y; P[4 * i + 2] = p.z; P[4 * i + 3] = p.w;
        }
    }

    // ---- load x (8) ----
    float x[8];
    {
        const float4* x4 = reinterpret_cast<const float4*>(x_est + sb * 8);
        float4 a = x4[0], c = x4[1];
        x[0] = a.x; x[1] = a.y; x[2] = a.z; x[3] = a.w;
        x[4] = c.x; x[5] = c.y; x[6] = c.z; x[7] = c.w;
    }

    // ---- x_pred = F x ----
    float xp[8];
#pragma unroll
    for (int i = 0; i < 8; ++i) {
        float s = 0.f;
#pragma unroll
        for (int j = 0; j < 8; ++j) s += Fr[i * 8 + j] * x[j];
        xp[i] = s;
    }

    // ---- T = F * P ----
    float T[64];
#pragma unroll
    for (int i = 0; i < 8; ++i)
#pragma unroll
        for (int j = 0; j < 8; ++j) {
            float s = 0.f;
#pragma unroll
            for (int k = 0; k < 8; ++k) s += Fr[i * 8 + k] * P[k * 8 + j];
            T[i * 8 + j] = s;
        }

    // ---- Pp = T * F^T + Q  (reuse P registers for Pp) ----
    {
        const float4* Q4 = reinterpret_cast<const float4*>(Qin + sb * 64);
        float Qr[64];
#pragma unroll
        for (int i = 0; i < 16; ++i) {
            float4 q = Q4[i];
            Qr[4 * i + 0] = q.x; Qr[4 * i + 1] = q.y; Qr[4 * i + 2] = q.z; Qr[4 * i + 3] = q.w;
        }
#pragma unroll
        for (int i = 0; i < 8; ++i)
#pragma unroll
            for (int j = 0; j < 8; ++j) {
                float s = Qr[i * 8 + j];
#pragma unroll
                for (int k = 0; k < 8; ++k) s += T[i * 8 + k] * Fr[j * 8 + k];
                P[i * 8 + j] = s;  // P now holds P_pred
            }
    }

    // ---- load H (4x8), R (4x4), z (4) ----
    float Hm[32], Rm[16], zv[4];
    {
        const float4* H4 = reinterpret_cast<const float4*>(Hin + sb * 32);
#pragma unroll
        for (int i = 0; i < 8; ++i) {
            float4 h = H4[i];
            Hm[4 * i + 0] = h.x; Hm[4 * i + 1] = h.y; Hm[4 * i + 2] = h.z; Hm[4 * i + 3] = h.w;
        }
        const float4* R4 = reinterpret_cast<const float4*>(Rin + sb * 16);
#pragma unroll
        for (int i = 0; i < 4; ++i) {
            float4 r = R4[i];
            Rm[4 * i + 0] = r.x; Rm[4 * i + 1] = r.y; Rm[4 * i + 2] = r.z; Rm[4 * i + 3] = r.w;
        }
        float4 zz = reinterpret_cast<const float4*>(zin + sb * 4)[0];
        zv[0] = zz.x; zv[1] = zz.y; zv[2] = zz.z; zv[3] = zz.w;
    }

    // ---- HP = H * Pp  (4x8) ----
    float HP[32];
#pragma unroll
    for (int i = 0; i < 4; ++i)
#pragma unroll
        for (int j = 0; j < 8; ++j) {
            float s = 0.f;
#pragma unroll
            for (int k = 0; k < 8; ++k) s += Hm[i * 8 + k] * P[k * 8 + j];
            HP[i * 8 + j] = s;
        }

    // ---- S = HP * H^T + R + eps*I  (4x4) ----
    float S[16];
#pragma unroll
    for (int i = 0; i < 4; ++i)
#pragma unroll
        for (int j = 0; j < 4; ++j) {
            float s = Rm[i * 4 + j];
#pragma unroll
            for (int k = 0; k < 8; ++k) s += HP[i * 8 + k] * Hm[j * 8 + k];
            if (i == j) s += EPS;
            S[i * 4 + j] = s;
        }

    // ---- Sinv = inv(S) via adjugate ----
    float inv[16];
    inv[0]  =  S[5]*S[10]*S[15] - S[5]*S[11]*S[14] - S[9]*S[6]*S[15] + S[9]*S[7]*S[14] + S[13]*S[6]*S[11] - S[13]*S[7]*S[10];
    inv[4]  = -S[4]*S[10]*S[15] + S[4]*S[11]*S[14] + S[8]*S[6]*S[15] - S[8]*S[7]*S[14] - S[12]*S[6]*S[11] + S[12]*S[7]*S[10];
    inv[8]  =  S[4]*S[9]*S[15]  - S[4]*S[11]*S[13] - S[8]*S[5]*S[15] + S[8]*S[7]*S[13] + S[12]*S[5]*S[11] - S[12]*S[7]*S[9];
    inv[12] = -S[4]*S[9]*S[14]  + S[4]*S[10]*S[13] + S[8]*S[5]*S[14] - S[8]*S[6]*S[13] - S[12]*S[5]*S[10] + S[12]*S[6]*S[9];
    inv[1]  = -S[1]*S[10]*S[15] + S[1]*S[11]*S[14] + S[9]*S[2]*S[15] - S[9]*S[3]*S[14] - S[13]*S[2]*S[11] + S[13]*S[3]*S[10];
    inv[5]  =  S[0]*S[10]*S[15] - S[0]*S[11]*S[14] - S[8]*S[2]*S[15] + S[8]*S[3]*S[14] + S[12]*S[2]*S[11] - S[12]*S[3]*S[10];
    inv[9]  = -S[0]*S[9]*S[15]  + S[0]*S[11]*S[13] + S[8]*S[1]*S[15] - S[8]*S[3]*S[13] - S[12]*S[1]*S[11] + S[12]*S[3]*S[9];
    inv[13] =  S[0]*S[9]*S[14]  - S[0]*S[10]*S[13] - S[8]*S[1]*S[14] + S[8]*S[2]*S[13] + S[12]*S[1]*S[10] - S[12]*S[2]*S[9];
    inv[2]  =  S[1]*S[6]*S[15]  - S[1]*S[7]*S[14]  - S[5]*S[2]*S[15] + S[5]*S[3]*S[14] + S[13]*S[2]*S[7]  - S[13]*S[3]*S[6];
    inv[6]  = -S[0]*S[6]*S[15]  + S[0]*S[7]*S[14]  + S[4]*S[2]*S[15] - S[4]*S[3]*S[14] - S[12]*S[2]*S[7]  + S[12]*S[3]*S[6];
    inv[10] =  S[0]*S[5]*S[15]  - S[0]*S[7]*S[13]  - S[4]*S[1]*S[15] + S[4]*S[3]*S[13] + S[12]*S[1]*S[7]  - S[12]*S[3]*S[5];
    inv[14] = -S[0]*S[5]*S[14]  + S[0]*S[6]*S[13]  + S[4]*S[1]*S[14] - S[4]*S[2]*S[13] - S[12]*S[1]*S[6]  + S[12]*S[2]*S[5];
    inv[3]  = -S[1]*S[6]*S[11]  + S[1]*S[7]*S[10]  + S[5]*S[2]*S[11] - S[5]*S[3]*S[10] - S[9]*S[2]*S[7]   + S[9]*S[3]*S[6];
    inv[7]  =  S[0]*S[6]*S[11]  - S[0]*S[7]*S[10]  - S[4]*S[2]*S[11] + S[4]*S[3]*S[10] + S[8]*S[2]*S[7]   - S[8]*S[3]*S[6];
    inv[11] = -S[0]*S[5]*S[11]  + S[0]*S[7]*S[9]   + S[4]*S[1]*S[11] - S[4]*S[3]*S[9]  - S[8]*S[1]*S[7]   + S[8]*S[3]*S[5];
    inv[15] =  S[0]*S[5]*S[10]  - S[0]*S[6]*S[9]   - S[4]*S[1]*S[10] + S[4]*S[2]*S[9]  + S[8]*S[1]*S[6]   - S[8]*S[2]*S[5];
    float det = S[0]*inv[0] + S[1]*inv[4] + S[2]*inv[8] + S[3]*inv[12];
    float rdet = 1.0f / det;
#pragma unroll
    for (int i = 0; i < 16; ++i) inv[i] *= rdet;

    // ---- PHT = Pp * H^T (8x4) ----
    float PHT[32];
#pragma unroll
    for (int i = 0; i < 8; ++i)
#pragma unroll
        for (int j = 0; j < 4; ++j) {
            float s = 0.f;
#pragma unroll
            for (int k = 0; k < 8; ++k) s += P[i * 8 + k] * Hm[j * 8 + k];
            PHT[i * 4 + j] = s;
        }

    // ---- K = PHT * Sinv (8x4) ----
    float K[32];
#pragma unroll
    for (int i = 0; i < 8; ++i)
#pragma unroll
        for (int j = 0; j < 4; ++j) {
            float s = 0.f;
#pragma unroll
            for (int k = 0; k < 4; ++k) s += PHT[i * 4 + k] * inv[k * 4 + j];
            K[i * 4 + j] = s;
        }

    // ---- y = z - H x_pred ----
    float y[4];
#pragma unroll
    for (int i = 0; i < 4; ++i) {
        float s = zv[i];
#pragma unroll
        for (int k = 0; k < 8; ++k) s -= Hm[i * 8 + k] * xp[k];
        y[i] = s;
    }

    // ---- x_new = x_pred + K y ----
    float xn[8];
#pragma unroll
    for (int i = 0; i < 8; ++i) {
        float s = xp[i];
#pragma unroll
        for (int k = 0; k < 4; ++k) s += K[i * 4 + k] * y[k];
        xn[i] = s;
    }

    // ---- P_new = Pp - K * HP ----
    float Pn[64];
#pragma unroll
    for (int i = 0; i < 8; ++i)
#pragma unroll
        for (int j = 0; j < 8; ++j) {
            float s = P[i * 8 + j];
#pragma unroll
            for (int k = 0; k < 4; ++k) s -= K[i * 4 + k] * HP[k * 8 + j];
            Pn[i * 8 + j] = s;
        }

    // ---- stores (flat concat: x_new, P_new, K) ----
    size_t Bz = (size_t)B;
    float4* xo = reinterpret_cast<float4*>(out + sb * 8);
    xo[0] = make_float4(xn[0], xn[1], xn[2], xn[3]);
    xo[1] = make_float4(xn[4], xn[5], xn[6], xn[7]);

    float4* po = reinterpret_cast<float4*>(out + Bz * 8 + sb * 64);
#pragma unroll
    for (int i = 0; i < 16; ++i)
        po[i] = make_float4(Pn[4 * i + 0], Pn[4 * i + 1], Pn[4 * i + 2], Pn[4 * i + 3]);

    float4* ko = reinterpret_cast<float4*>(out + Bz * 72 + sb * 32);
#pragma unroll
    for (int i = 0; i < 8; ++i)
        ko[i] = make_float4(K[4 * i + 0], K[4 * i + 1], K[4 * i + 2], K[4 * i + 3]);
}

extern "C" void kernel_launch(void* const* d_in, const int* in_sizes, int n_in,
                              void* d_out, int out_size, void* d_ws, size_t ws_size,
                              hipStream_t stream) {
    const float* x_est = (const float*)d_in[0];
    const float* P_est = (const float*)d_in[1];
    const float* F     = (const float*)d_in[2];
    const float* Q     = (const float*)d_in[3];
    const float* z     = (const float*)d_in[4];
    const float* H     = (const float*)d_in[5];
    const float* R     = (const float*)d_in[6];
    float* out = (float*)d_out;
    int B = in_sizes[0] / 8;
    int block = 256;
    int grid = (B + block - 1) / block;
    kf_kernel<<<grid, block, 0, stream>>>(x_est, P_est, F, Q, z, H, R, out, B);
}

// Round 2
// 487.408 us; speedup vs baseline: 1.7015x; 1.7015x over previous
//
#include <hip/hip_runtime.h>

// Batched Kalman filter: B batches, N=8 state, M=4 measurement, fp32.
// One thread per batch; fully unrolled, register-resident.
// __launch_bounds__(256,2): VGPR cap 256 (2 waves/SIMD) — without it the
// compiler assumed 1024-thread workgroups, capped at 64 VGPR, and spilled
// ~1.7 GB of scratch through HBM (R1: WRITE_SIZE 1.25 GB vs 109 MB ideal).
// Peak live set kept < ~220 floats:
//   - Q streamed row-wise into Pp accumulation (no Q[64] array)
//   - P_pred is symmetric => P_pred H^T = (H P_pred)^T, no PHT array
//   - P_new computed row-wise and stored immediately (no Pn[64] array)
// Outputs flat-concatenated: x_new[B*8], P_new[B*64], K[B*32].

#define EPS 1e-6f

__global__ __launch_bounds__(256, 2)
void kf_kernel(const float* __restrict__ x_est,
               const float* __restrict__ P_est,
               const float* __restrict__ Fin,
               const float* __restrict__ Qin,
               const float* __restrict__ zin,
               const float* __restrict__ Hin,
               const float* __restrict__ Rin,
               float* __restrict__ out, int B) {
    int b = blockIdx.x * blockDim.x + threadIdx.x;
    if (b >= B) return;
    size_t sb = (size_t)b;

    // ---- load F (8x8) ----
    float Fr[64];
    {
        const float4* F4 = reinterpret_cast<const float4*>(Fin + sb * 64);
#pragma unroll
        for (int i = 0; i < 16; ++i) {
            float4 f = F4[i];
            Fr[4 * i + 0] = f.x; Fr[4 * i + 1] = f.y; Fr[4 * i + 2] = f.z; Fr[4 * i + 3] = f.w;
        }
    }

    // ---- x_pred = F x ----
    float xp[8];
    {
        const float4* x4 = reinterpret_cast<const float4*>(x_est + sb * 8);
        float4 a = x4[0], c = x4[1];
        float x[8] = {a.x, a.y, a.z, a.w, c.x, c.y, c.z, c.w};
#pragma unroll
        for (int i = 0; i < 8; ++i) {
            float s = 0.f;
#pragma unroll
            for (int j = 0; j < 8; ++j) s += Fr[i * 8 + j] * x[j];
            xp[i] = s;
        }
    }

    // ---- T = F * P  (P scoped: dies after this block) ----
    float T[64];
    {
        float P[64];
        const float4* P4 = reinterpret_cast<const float4*>(P_est + sb * 64);
#pragma unroll
        for (int i = 0; i < 16; ++i) {
            float4 p = P4[i];
            P[4 * i + 0] = p.x; P[4 * i + 1] = p.y; P[4 * i + 2] = p.z; P[4 * i + 3] = p.w;
        }
#pragma unroll
        for (int i = 0; i < 8; ++i)
#pragma unroll
            for (int j = 0; j < 8; ++j) {
                float s = 0.f;
#pragma unroll
                for (int k = 0; k < 8; ++k) s += Fr[i * 8 + k] * P[k * 8 + j];
                T[i * 8 + j] = s;
            }
    }

    // ---- Pp = T * F^T + Q  (Q streamed one row at a time) ----
    float Pp[64];
    {
        const float4* Q4 = reinterpret_cast<const float4*>(Qin + sb * 64);
#pragma unroll
        for (int i = 0; i < 8; ++i) {
            float4 qa = Q4[2 * i], qb = Q4[2 * i + 1];
            float Qr[8] = {qa.x, qa.y, qa.z, qa.w, qb.x, qb.y, qb.z, qb.w};
#pragma unroll
            for (int j = 0; j < 8; ++j) {
                float s = Qr[j];
#pragma unroll
                for (int k = 0; k < 8; ++k) s += T[i * 8 + k] * Fr[j * 8 + k];
                Pp[i * 8 + j] = s;
            }
        }
    }
    // F and T dead here.

    // ---- load H (4x8) ----
    float Hm[32];
    {
        const float4* H4 = reinterpret_cast<const float4*>(Hin + sb * 32);
#pragma unroll
        for (int i = 0; i < 8; ++i) {
            float4 h = H4[i];
            Hm[4 * i + 0] = h.x; Hm[4 * i + 1] = h.y; Hm[4 * i + 2] = h.z; Hm[4 * i + 3] = h.w;
        }
    }

    // ---- HP = H * Pp  (4x8) ----
    float HP[32];
#pragma unroll
    for (int i = 0; i < 4; ++i)
#pragma unroll
        for (int j = 0; j < 8; ++j) {
            float s = 0.f;
#pragma unroll
            for (int k = 0; k < 8; ++k) s += Hm[i * 8 + k] * Pp[k * 8 + j];
            HP[i * 8 + j] = s;
        }

    // ---- S = HP * H^T + R + eps*I  (4x4, R streamed) ----
    float S[16];
    {
        const float4* R4 = reinterpret_cast<const float4*>(Rin + sb * 16);
#pragma unroll
        for (int i = 0; i < 4; ++i) {
            float4 r = R4[i];
            float Rr[4] = {r.x, r.y, r.z, r.w};
#pragma unroll
            for (int j = 0; j < 4; ++j) {
                float s = Rr[j];
#pragma unroll
                for (int k = 0; k < 8; ++k) s += HP[i * 8 + k] * Hm[j * 8 + k];
                if (i == j) s += EPS;
                S[i * 4 + j] = s;
            }
        }
    }

    // ---- y = z - H x_pred  (kills H's last use besides nothing: H dead after) ----
    float y[4];
    {
        float4 zz = reinterpret_cast<const float4*>(zin + sb * 4)[0];
        float zv[4] = {zz.x, zz.y, zz.z, zz.w};
#pragma unroll
        for (int i = 0; i < 4; ++i) {
            float s = zv[i];
#pragma unroll
            for (int k = 0; k < 8; ++k) s -= Hm[i * 8 + k] * xp[k];
            y[i] = s;
        }
    }
    // H dead here.

    // ---- Sinv via adjugate ----
    float inv[16];
    inv[0]  =  S[5]*S[10]*S[15] - S[5]*S[11]*S[14] - S[9]*S[6]*S[15] + S[9]*S[7]*S[14] + S[13]*S[6]*S[11] - S[13]*S[7]*S[10];
    inv[4]  = -S[4]*S[10]*S[15] + S[4]*S[11]*S[14] + S[8]*S[6]*S[15] - S[8]*S[7]*S[14] - S[12]*S[6]*S[11] + S[12]*S[7]*S[10];
    inv[8]  =  S[4]*S[9]*S[15]  - S[4]*S[11]*S[13] - S[8]*S[5]*S[15] + S[8]*S[7]*S[13] + S[12]*S[5]*S[11] - S[12]*S[7]*S[9];
    inv[12] = -S[4]*S[9]*S[14]  + S[4]*S[10]*S[13] + S[8]*S[5]*S[14] - S[8]*S[6]*S[13] - S[12]*S[5]*S[10] + S[12]*S[6]*S[9];
    inv[1]  = -S[1]*S[10]*S[15] + S[1]*S[11]*S[14] + S[9]*S[2]*S[15] - S[9]*S[3]*S[14] - S[13]*S[2]*S[11] + S[13]*S[3]*S[10];
    inv[5]  =  S[0]*S[10]*S[15] - S[0]*S[11]*S[14] - S[8]*S[2]*S[15] + S[8]*S[3]*S[14] + S[12]*S[2]*S[11] - S[12]*S[3]*S[10];
    inv[9]  = -S[0]*S[9]*S[15]  + S[0]*S[11]*S[13] + S[8]*S[1]*S[15] - S[8]*S[3]*S[13] - S[12]*S[1]*S[11] + S[12]*S[3]*S[9];
    inv[13] =  S[0]*S[9]*S[14]  - S[0]*S[10]*S[13] - S[8]*S[1]*S[14] + S[8]*S[2]*S[13] + S[12]*S[1]*S[10] - S[12]*S[2]*S[9];
    inv[2]  =  S[1]*S[6]*S[15]  - S[1]*S[7]*S[14]  - S[5]*S[2]*S[15] + S[5]*S[3]*S[14] + S[13]*S[2]*S[7]  - S[13]*S[3]*S[6];
    inv[6]  = -S[0]*S[6]*S[15]  + S[0]*S[7]*S[14]  + S[4]*S[2]*S[15] - S[4]*S[3]*S[14] - S[12]*S[2]*S[7]  + S[12]*S[3]*S[6];
    inv[10] =  S[0]*S[5]*S[15]  - S[0]*S[7]*S[13]  - S[4]*S[1]*S[15] + S[4]*S[3]*S[13] + S[12]*S[1]*S[7]  - S[12]*S[3]*S[5];
    inv[14] = -S[0]*S[5]*S[14]  + S[0]*S[6]*S[13]  + S[4]*S[1]*S[14] - S[4]*S[2]*S[13] - S[12]*S[1]*S[6]  + S[12]*S[2]*S[5];
    inv[3]  = -S[1]*S[6]*S[11]  + S[1]*S[7]*S[10]  + S[5]*S[2]*S[11] - S[5]*S[3]*S[10] - S[9]*S[2]*S[7]   + S[9]*S[3]*S[6];
    inv[7]  =  S[0]*S[6]*S[11]  - S[0]*S[7]*S[10]  - S[4]*S[2]*S[11] + S[4]*S[3]*S[10] + S[8]*S[2]*S[7]   - S[8]*S[3]*S[6];
    inv[11] = -S[0]*S[5]*S[11]  + S[0]*S[7]*S[9]   + S[4]*S[1]*S[11] - S[4]*S[3]*S[9]  - S[8]*S[1]*S[7]   + S[8]*S[3]*S[5];
    inv[15] =  S[0]*S[5]*S[10]  - S[0]*S[6]*S[9]   - S[4]*S[1]*S[10] + S[4]*S[2]*S[9]  + S[8]*S[1]*S[6]   - S[8]*S[2]*S[5];
    float det = S[0]*inv[0] + S[1]*inv[4] + S[2]*inv[8] + S[3]*inv[12];
    float rdet = 1.0f / det;
#pragma unroll
    for (int i = 0; i < 16; ++i) inv[i] *= rdet;
    // S dead here.

    // ---- K = Pp H^T Sinv = (HP)^T * Sinv  (Pp symmetric) ----
    float K[32];
#pragma unroll
    for (int i = 0; i < 8; ++i)
#pragma unroll
        for (int j = 0; j < 4; ++j) {
            float s = 0.f;
#pragma unroll
            for (int k = 0; k < 4; ++k) s += HP[k * 8 + i] * inv[k * 4 + j];
            K[i * 4 + j] = s;
        }
    // inv dead here.

    size_t Bz = (size_t)B;

    // ---- x_new = x_pred + K y; store ----
    {
        float xn[8];
#pragma unroll
        for (int i = 0; i < 8; ++i) {
            float s = xp[i];
#pragma unroll
            for (int k = 0; k < 4; ++k) s += K[i * 4 + k] * y[k];
            xn[i] = s;
        }
        float4* xo = reinterpret_cast<float4*>(out + sb * 8);
        xo[0] = make_float4(xn[0], xn[1], xn[2], xn[3]);
        xo[1] = make_float4(xn[4], xn[5], xn[6], xn[7]);
    }

    // ---- P_new = Pp - K*HP, row-wise, stored immediately ----
    {
        float4* po = reinterpret_cast<float4*>(out + Bz * 8 + sb * 64);
#pragma unroll
        for (int i = 0; i < 8; ++i) {
            float r[8];
#pragma unroll
            for (int j = 0; j < 8; ++j) {
                float s = Pp[i * 8 + j];
#pragma unroll
                for (int k = 0; k < 4; ++k) s -= K[i * 4 + k] * HP[k * 8 + j];
                r[j] = s;
            }
            po[2 * i + 0] = make_float4(r[0], r[1], r[2], r[3]);
            po[2 * i + 1] = make_float4(r[4], r[5], r[6], r[7]);
        }
    }

    // ---- store K ----
    {
        float4* ko = reinterpret_cast<float4*>(out + Bz * 72 + sb * 32);
#pragma unroll
        for (int i = 0; i < 8; ++i)
            ko[i] = make_float4(K[4 * i + 0], K[4 * i + 1], K[4 * i + 2], K[4 * i + 3]);
    }
}

extern "C" void kernel_launch(void* const* d_in, const int* in_sizes, int n_in,
                              void* d_out, int out_size, void* d_ws, size_t ws_size,
                              hipStream_t stream) {
    const float* x_est = (const float*)d_in[0];
    const float* P_est = (const float*)d_in[1];
    const float* F     = (const float*)d_in[2];
    const float* Q     = (const float*)d_in[3];
    const float* z     = (const float*)d_in[4];
    const float* H     = (const float*)d_in[5];
    const float* R     = (const float*)d_in[6];
    float* out = (float*)d_out;
    int B = in_sizes[0] / 8;
    int block = 256;
    int grid = (B + block - 1) / block;
    kf_kernel<<<grid, block, 0, stream>>>(x_est, P_est, F, Q, z, H, R, out, B);
}

// Round 3
// 334.694 us; speedup vs baseline: 2.4778x; 1.4563x over previous
//
#include <hip/hip_runtime.h>

// Batched Kalman filter: B batches, N=8 state, M=4 measurement, fp32.
// One thread per batch; fully unrolled, register-resident.
//
// R1: no launch bounds -> 64 VGPR cap -> ~1.7 GB spill traffic, 645 us.
// R2: __launch_bounds__(256,2) only sets MIN waves/EU; allocator still
//     targeted 4 waves/EU (128 VGPR) and spilled ~400 MB, 304 us.
// R3: amdgpu_waves_per_eu(2,2) pins occupancy at 2 waves/EU -> 256 VGPR
//     budget, AND live set shrunk to ~170 floats via symmetric storage:
//     P_est / P_pred are PSD -> keep lower triangle only (36 floats each),
//     predict fused row-wise (T_i = F_i*P is an 8-float transient).
// Outputs flat-concatenated: x_new[B*8], P_new[B*64], K[B*32].

#define EPS 1e-6f

// symmetric lower-triangle index (r >= c): r*(r+1)/2 + c
#define SYMIDX(r, c) ((r) * ((r) + 1) / 2 + (c))

__global__ __launch_bounds__(256) __attribute__((amdgpu_waves_per_eu(2, 2)))
void kf_kernel(const float* __restrict__ x_est,
               const float* __restrict__ P_est,
               const float* __restrict__ Fin,
               const float* __restrict__ Qin,
               const float* __restrict__ zin,
               const float* __restrict__ Hin,
               const float* __restrict__ Rin,
               float* __restrict__ out, int B) {
    int b = blockIdx.x * blockDim.x + threadIdx.x;
    if (b >= B) return;
    size_t sb = (size_t)b;

    // ---- load F (8x8) ----
    float Fr[64];
    {
        const float4* F4 = reinterpret_cast<const float4*>(Fin + sb * 64);
#pragma unroll
        for (int i = 0; i < 16; ++i) {
            float4 f = F4[i];
            Fr[4 * i + 0] = f.x; Fr[4 * i + 1] = f.y; Fr[4 * i + 2] = f.z; Fr[4 * i + 3] = f.w;
        }
    }

    // ---- load P lower triangle (36) ----
    float Ps[36];
    {
        const float4* P4 = reinterpret_cast<const float4*>(P_est + sb * 64);
#pragma unroll
        for (int i = 0; i < 8; ++i) {
            float4 pa = P4[2 * i], pb = P4[2 * i + 1];
            float row[8] = {pa.x, pa.y, pa.z, pa.w, pb.x, pb.y, pb.z, pb.w};
#pragma unroll
            for (int j = 0; j < 8; ++j)
                if (j <= i) Ps[SYMIDX(i, j)] = row[j];
        }
    }

    // ---- x_pred = F x ----
    float xp[8];
    {
        const float4* x4 = reinterpret_cast<const float4*>(x_est + sb * 8);
        float4 a = x4[0], c = x4[1];
        float x[8] = {a.x, a.y, a.z, a.w, c.x, c.y, c.z, c.w};
#pragma unroll
        for (int i = 0; i < 8; ++i) {
            float s = 0.f;
#pragma unroll
            for (int j = 0; j < 8; ++j) s += Fr[i * 8 + j] * x[j];
            xp[i] = s;
        }
    }

    // ---- Pp(sym) = F P F^T + Q, fused row-wise ----
    // T_i = F_i * P (8-float transient), then Pp[i][j] = T_i . F_j + Q[i][j], j<=i
    float Pps[36];
    {
        const float4* Q4 = reinterpret_cast<const float4*>(Qin + sb * 64);
#pragma unroll
        for (int i = 0; i < 8; ++i) {
            float Ti[8];
#pragma unroll
            for (int j = 0; j < 8; ++j) {
                float s = 0.f;
#pragma unroll
                for (int k = 0; k < 8; ++k) {
                    float pkj = (k >= j) ? Ps[SYMIDX(k, j)] : Ps[SYMIDX(j, k)];
                    s += Fr[i * 8 + k] * pkj;
                }
                Ti[j] = s;
            }
            float4 qa = Q4[2 * i], qb = Q4[2 * i + 1];
            float Qr[8] = {qa.x, qa.y, qa.z, qa.w, qb.x, qb.y, qb.z, qb.w};
#pragma unroll
            for (int j = 0; j <= i; ++j) {
                float s = Qr[j];
#pragma unroll
                for (int k = 0; k < 8; ++k) s += Ti[k] * Fr[j * 8 + k];
                Pps[SYMIDX(i, j)] = s;
            }
        }
    }
    // F, Ps dead here.

    // ---- load H (4x8) ----
    float Hm[32];
    {
        const float4* H4 = reinterpret_cast<const float4*>(Hin + sb * 32);
#pragma unroll
        for (int i = 0; i < 8; ++i) {
            float4 h = H4[i];
            Hm[4 * i + 0] = h.x; Hm[4 * i + 1] = h.y; Hm[4 * i + 2] = h.z; Hm[4 * i + 3] = h.w;
        }
    }

    // ---- HP = H * Pp  (4x8) ----
    float HP[32];
#pragma unroll
    for (int i = 0; i < 4; ++i)
#pragma unroll
        for (int j = 0; j < 8; ++j) {
            float s = 0.f;
#pragma unroll
            for (int k = 0; k < 8; ++k) {
                float pkj = (k >= j) ? Pps[SYMIDX(k, j)] : Pps[SYMIDX(j, k)];
                s += Hm[i * 8 + k] * pkj;
            }
            HP[i * 8 + j] = s;
        }

    // ---- S = HP * H^T + R + eps*I  (4x4, R streamed) ----
    float S[16];
    {
        const float4* R4 = reinterpret_cast<const float4*>(Rin + sb * 16);
#pragma unroll
        for (int i = 0; i < 4; ++i) {
            float4 r = R4[i];
            float Rr[4] = {r.x, r.y, r.z, r.w};
#pragma unroll
            for (int j = 0; j < 4; ++j) {
                float s = Rr[j];
#pragma unroll
                for (int k = 0; k < 8; ++k) s += HP[i * 8 + k] * Hm[j * 8 + k];
                if (i == j) s += EPS;
                S[i * 4 + j] = s;
            }
        }
    }

    // ---- y = z - H x_pred ----
    float y[4];
    {
        float4 zz = reinterpret_cast<const float4*>(zin + sb * 4)[0];
        float zv[4] = {zz.x, zz.y, zz.z, zz.w};
#pragma unroll
        for (int i = 0; i < 4; ++i) {
            float s = zv[i];
#pragma unroll
            for (int k = 0; k < 8; ++k) s -= Hm[i * 8 + k] * xp[k];
            y[i] = s;
        }
    }
    // H dead here.

    // ---- Sinv via adjugate ----
    float inv[16];
    inv[0]  =  S[5]*S[10]*S[15] - S[5]*S[11]*S[14] - S[9]*S[6]*S[15] + S[9]*S[7]*S[14] + S[13]*S[6]*S[11] - S[13]*S[7]*S[10];
    inv[4]  = -S[4]*S[10]*S[15] + S[4]*S[11]*S[14] + S[8]*S[6]*S[15] - S[8]*S[7]*S[14] - S[12]*S[6]*S[11] + S[12]*S[7]*S[10];
    inv[8]  =  S[4]*S[9]*S[15]  - S[4]*S[11]*S[13] - S[8]*S[5]*S[15] + S[8]*S[7]*S[13] + S[12]*S[5]*S[11] - S[12]*S[7]*S[9];
    inv[12] = -S[4]*S[9]*S[14]  + S[4]*S[10]*S[13] + S[8]*S[5]*S[14] - S[8]*S[6]*S[13] - S[12]*S[5]*S[10] + S[12]*S[6]*S[9];
    inv[1]  = -S[1]*S[10]*S[15] + S[1]*S[11]*S[14] + S[9]*S[2]*S[15] - S[9]*S[3]*S[14] - S[13]*S[2]*S[11] + S[13]*S[3]*S[10];
    inv[5]  =  S[0]*S[10]*S[15] - S[0]*S[11]*S[14] - S[8]*S[2]*S[15] + S[8]*S[3]*S[14] + S[12]*S[2]*S[11] - S[12]*S[3]*S[10];
    inv[9]  = -S[0]*S[9]*S[15]  + S[0]*S[11]*S[13] + S[8]*S[1]*S[15] - S[8]*S[3]*S[13] - S[12]*S[1]*S[11] + S[12]*S[3]*S[9];
    inv[13] =  S[0]*S[9]*S[14]  - S[0]*S[10]*S[13] - S[8]*S[1]*S[14] + S[8]*S[2]*S[13] + S[12]*S[1]*S[10] - S[12]*S[2]*S[9];
    inv[2]  =  S[1]*S[6]*S[15]  - S[1]*S[7]*S[14]  - S[5]*S[2]*S[15] + S[5]*S[3]*S[14] + S[13]*S[2]*S[7]  - S[13]*S[3]*S[6];
    inv[6]  = -S[0]*S[6]*S[15]  + S[0]*S[7]*S[14]  + S[4]*S[2]*S[15] - S[4]*S[3]*S[14] - S[12]*S[2]*S[7]  + S[12]*S[3]*S[6];
    inv[10] =  S[0]*S[5]*S[15]  - S[0]*S[7]*S[13]  - S[4]*S[1]*S[15] + S[4]*S[3]*S[13] + S[12]*S[1]*S[7]  - S[12]*S[3]*S[5];
    inv[14] = -S[0]*S[5]*S[14]  + S[0]*S[6]*S[13]  + S[4]*S[1]*S[14] - S[4]*S[2]*S[13] - S[12]*S[1]*S[6]  + S[12]*S[2]*S[5];
    inv[3]  = -S[1]*S[6]*S[11]  + S[1]*S[7]*S[10]  + S[5]*S[2]*S[11] - S[5]*S[3]*S[10] - S[9]*S[2]*S[7]   + S[9]*S[3]*S[6];
    inv[7]  =  S[0]*S[6]*S[11]  - S[0]*S[7]*S[10]  - S[4]*S[2]*S[11] + S[4]*S[3]*S[10] + S[8]*S[2]*S[7]   - S[8]*S[3]*S[6];
    inv[11] = -S[0]*S[5]*S[11]  + S[0]*S[7]*S[9]   + S[4]*S[1]*S[11] - S[4]*S[3]*S[9]  - S[8]*S[1]*S[7]   + S[8]*S[3]*S[5];
    inv[15] =  S[0]*S[5]*S[10]  - S[0]*S[6]*S[9]   - S[4]*S[1]*S[10] + S[4]*S[2]*S[9]  + S[8]*S[1]*S[6]   - S[8]*S[2]*S[5];
    float det = S[0]*inv[0] + S[1]*inv[4] + S[2]*inv[8] + S[3]*inv[12];
    float rdet = 1.0f / det;
#pragma unroll
    for (int i = 0; i < 16; ++i) inv[i] *= rdet;
    // S dead here.

    // ---- K = Pp H^T Sinv = (HP)^T * Sinv  (Pp symmetric) ----
    float K[32];
#pragma unroll
    for (int i = 0; i < 8; ++i)
#pragma unroll
        for (int j = 0; j < 4; ++j) {
            float s = 0.f;
#pragma unroll
            for (int k = 0; k < 4; ++k) s += HP[k * 8 + i] * inv[k * 4 + j];
            K[i * 4 + j] = s;
        }
    // inv dead here.

    size_t Bz = (size_t)B;

    // ---- x_new = x_pred + K y; store ----
    {
        float xn[8];
#pragma unroll
        for (int i = 0; i < 8; ++i) {
            float s = xp[i];
#pragma unroll
            for (int k = 0; k < 4; ++k) s += K[i * 4 + k] * y[k];
            xn[i] = s;
        }
        float4* xo = reinterpret_cast<float4*>(out + sb * 8);
        xo[0] = make_float4(xn[0], xn[1], xn[2], xn[3]);
        xo[1] = make_float4(xn[4], xn[5], xn[6], xn[7]);
    }

    // ---- P_new = Pp - K*HP, row-wise, stored immediately ----
    {
        float4* po = reinterpret_cast<float4*>(out + Bz * 8 + sb * 64);
#pragma unroll
        for (int i = 0; i < 8; ++i) {
            float r[8];
#pragma unroll
            for (int j = 0; j < 8; ++j) {
                float pij = (i >= j) ? Pps[SYMIDX(i, j)] : Pps[SYMIDX(j, i)];
                float s = pij;
#pragma unroll
                for (int k = 0; k < 4; ++k) s -= K[i * 4 + k] * HP[k * 8 + j];
                r[j] = s;
            }
            po[2 * i + 0] = make_float4(r[0], r[1], r[2], r[3]);
            po[2 * i + 1] = make_float4(r[4], r[5], r[6], r[7]);
        }
    }

    // ---- store K ----
    {
        float4* ko = reinterpret_cast<float4*>(out + Bz * 72 + sb * 32);
#pragma unroll
        for (int i = 0; i < 8; ++i)
            ko[i] = make_float4(K[4 * i + 0], K[4 * i + 1], K[4 * i + 2], K[4 * i + 3]);
    }
}

extern "C" void kernel_launch(void* const* d_in, const int* in_sizes, int n_in,
                              void* d_out, int out_size, void* d_ws, size_t ws_size,
                              hipStream_t stream) {
    const float* x_est = (const float*)d_in[0];
    const float* P_est = (const float*)d_in[1];
    const float* F     = (const float*)d_in[2];
    const float* Q     = (const float*)d_in[3];
    const float* z     = (const float*)d_in[4];
    const float* H     = (const float*)d_in[5];
    const float* R     = (const float*)d_in[6];
    float* out = (float*)d_out;
    int B = in_sizes[0] / 8;
    int block = 256;
    int grid = (B + block - 1) / block;
    kf_kernel<<<grid, block, 0, stream>>>(x_est, P_est, F, Q, z, H, R, out, B);
}